// Round 7
// baseline (454.567 us; speedup 1.0000x reference)
//
#include <hip/hip_runtime.h>

#define B_ 16384
#define E_ 1024
#define H_ 8
#define D_ 128

typedef _Float16 f16;
typedef _Float16 f16x8 __attribute__((ext_vector_type(8)));
typedef float f32x4 __attribute__((ext_vector_type(4)));

// async global -> LDS, 16B per lane. LDS dest is wave-uniform base + lane*16.
__device__ __forceinline__ void gload16(const f16* g, f16* l) {
    __builtin_amdgcn_global_load_lds(
        (const __attribute__((address_space(1))) void*)g,
        (__attribute__((address_space(3))) void*)l, 16, 0, 0);
}

// LDS XOR swizzle (within each 16-row x 32-col f16 tile staged by one gload16):
//   LDS chunk p (16B) of row r holds global chunk p ^ ((r>>1)&3).
// Write side: lane l (r=l>>2, p=l&3) sources global chunk (l&3)^((l>>3)&3).
// Read side: global chunk lq of row r lives at LDS chunk lq^((r>>1)&3).
// Verified round 2: SQ_LDS_BANK_CONFLICT 1.68e7 -> 0.

// ---------------- f32 -> f16 conversion, all 6 tensors, one launch ------------
__global__ __launch_bounds__(256) void cvt6_kernel(
    const float4* __restrict__ xi, const float4* __restrict__ xs,
    const float4* __restrict__ wq, const float4* __restrict__ wk,
    const float4* __restrict__ wv, const float4* __restrict__ wo,
    ushort4* __restrict__ dxi, ushort4* __restrict__ dxs,
    ushort4* __restrict__ dwq, ushort4* __restrict__ dwk,
    ushort4* __restrict__ dwv, ushort4* __restrict__ dwo)
{
    int b = blockIdx.x;
    const float4* s; ushort4* d;
    if (b < 32768) {
        if (b < 16384) { s = xi; d = dxi; }
        else           { s = xs; d = dxs; b -= 16384; }
    } else {
        b -= 32768;
        int w = b >> 10; b &= 1023;
        switch (w) {
            case 0:  s = wq; d = dwq; break;
            case 1:  s = wk; d = dwk; break;
            case 2:  s = wv; d = dwv; break;
            default: s = wo; d = dwo; break;
        }
    }
    size_t i = (size_t)b * 256 + threadIdx.x;
    float4 v = s[i];
    union { ushort4 u; f16 h[4]; } o;
    o.h[0] = (f16)v.x; o.h[1] = (f16)v.y; o.h[2] = (f16)v.z; o.h[3] = (f16)v.w;
    d[i] = o.u;
}

// ---------------- fused single-pass QKV + 2-key attention -> ctx ----------------
// grid (B/64, H): 2-D (r2-proven FETCH=156MB; r4's head-per-XCD 1-D raised it to
// 274MB). 256 threads = 4 waves, wave grid 2x2 over 64 rows x 128 head cols.
// One K-pass computes Q, Kimg, Ksig, Vimg, Vsig; epilogue mixes ctx = a0*Vi+a1*Vs.
// Single-buffer BK=64 (measured best: r2 195 BK32, r3 234 dbuf-drain0, r4 191 BK64).
__global__ __launch_bounds__(256, 2) void qkv_attn_kernel(
    const f16* __restrict__ Xi, const f16* __restrict__ Xs,
    const f16* __restrict__ Wq, const f16* __restrict__ Wk, const f16* __restrict__ Wv,
    const float* __restrict__ bq, const float* __restrict__ bk, const float* __restrict__ bv,
    f16* __restrict__ ctx)
{
    __shared__ f16 sAi[2][64][32];    // [half][row][col]  8 KB
    __shared__ f16 sAs[2][64][32];    //                   8 KB
    __shared__ f16 sWq[2][128][32];   //                  16 KB
    __shared__ f16 sWk[2][128][32];   //                  16 KB
    __shared__ f16 sWv[2][128][32];   //                  16 KB  (64 KB -> 2 blocks/CU)
    __shared__ float sdot[2][64][2];
    __shared__ float sa0[64];

    const int tid  = threadIdx.x;
    const int lane = tid & 63;
    const int wave = tid >> 6;
    const int wr = wave >> 1, wc = wave & 1;
    const int l16 = lane & 15, lq = lane >> 4;

    const int row0 = blockIdx.x * 64;
    const int col0 = blockIdx.y * D_;   // head slice in E

    const int lr = lane >> 2;                                   // 0..15
    const int lc = ((lane & 3) ^ ((lane >> 3) & 3)) * 8;        // swizzled src chunk
    const int rc = (lq ^ ((l16 >> 1) & 3)) * 8;                 // swizzled read col

    const f16* gAi = Xi + (size_t)(row0 + wave * 16 + lr) * E_ + lc;
    const f16* gAs = Xs + (size_t)(row0 + wave * 16 + lr) * E_ + lc;
    const size_t woff = (size_t)(col0 + wave * 32 + lr) * E_ + lc;
    const f16* gWq = Wq + woff;
    const f16* gWk = Wk + woff;
    const f16* gWv = Wv + woff;
    const size_t wskip = (size_t)16 * E_;

    f32x4 zero4 = {0.f, 0.f, 0.f, 0.f};
    f32x4 accQ[2][4], accKi[2][4], accKs[2][4], accVi[2][4], accVs[2][4];
    #pragma unroll
    for (int i = 0; i < 2; i++)
        #pragma unroll
        for (int j = 0; j < 4; j++) {
            accQ[i][j] = zero4; accKi[i][j] = zero4; accKs[i][j] = zero4;
            accVi[i][j] = zero4; accVs[i][j] = zero4;
        }

    for (int kk = 0; kk < E_; kk += 64) {
        #pragma unroll
        for (int h = 0; h < 2; h++) {
            const int ko = kk + h * 32;
            gload16(gAi + ko,         &sAi[h][wave * 16][0]);
            gload16(gAs + ko,         &sAs[h][wave * 16][0]);
            gload16(gWq + ko,         &sWq[h][wave * 32][0]);
            gload16(gWq + wskip + ko, &sWq[h][wave * 32 + 16][0]);
            gload16(gWk + ko,         &sWk[h][wave * 32][0]);
            gload16(gWk + wskip + ko, &sWk[h][wave * 32 + 16][0]);
            gload16(gWv + ko,         &sWv[h][wave * 32][0]);
            gload16(gWv + wskip + ko, &sWv[h][wave * 32 + 16][0]);
        }
        __syncthreads();   // drains vmcnt -> tile resident

        #pragma unroll
        for (int h = 0; h < 2; h++) {
            f16x8 aI[2], aS[2], bF[4];
            #pragma unroll
            for (int fr = 0; fr < 2; fr++) {
                aI[fr] = *(const f16x8*)&sAi[h][wr * 32 + fr * 16 + l16][rc];
                aS[fr] = *(const f16x8*)&sAs[h][wr * 32 + fr * 16 + l16][rc];
            }
            #pragma unroll
            for (int fc = 0; fc < 4; fc++)
                bF[fc] = *(const f16x8*)&sWq[h][wc * 64 + fc * 16 + l16][rc];
            #pragma unroll
            for (int fr = 0; fr < 2; fr++)
                #pragma unroll
                for (int fc = 0; fc < 4; fc++)
                    accQ[fr][fc] = __builtin_amdgcn_mfma_f32_16x16x32_f16(aI[fr], bF[fc], accQ[fr][fc], 0, 0, 0);
            #pragma unroll
            for (int fc = 0; fc < 4; fc++)
                bF[fc] = *(const f16x8*)&sWk[h][wc * 64 + fc * 16 + l16][rc];
            #pragma unroll
            for (int fr = 0; fr < 2; fr++)
                #pragma unroll
                for (int fc = 0; fc < 4; fc++) {
                    accKi[fr][fc] = __builtin_amdgcn_mfma_f32_16x16x32_f16(aI[fr], bF[fc], accKi[fr][fc], 0, 0, 0);
                    accKs[fr][fc] = __builtin_amdgcn_mfma_f32_16x16x32_f16(aS[fr], bF[fc], accKs[fr][fc], 0, 0, 0);
                }
            #pragma unroll
            for (int fc = 0; fc < 4; fc++)
                bF[fc] = *(const f16x8*)&sWv[h][wc * 64 + fc * 16 + l16][rc];
            #pragma unroll
            for (int fr = 0; fr < 2; fr++)
                #pragma unroll
                for (int fc = 0; fc < 4; fc++) {
                    accVi[fr][fc] = __builtin_amdgcn_mfma_f32_16x16x32_f16(aI[fr], bF[fc], accVi[fr][fc], 0, 0, 0);
                    accVs[fr][fc] = __builtin_amdgcn_mfma_f32_16x16x32_f16(aS[fr], bF[fc], accVs[fr][fc], 0, 0, 0);
                }
        }
        __syncthreads();   // guard LDS reuse next iteration
    }

    #pragma unroll
    for (int fc = 0; fc < 4; fc++) {
        int col = col0 + wc * 64 + fc * 16 + l16;
        float bqv = bq[col], bkv = bk[col];
        #pragma unroll
        for (int fr = 0; fr < 2; fr++)
            #pragma unroll
            for (int e = 0; e < 4; e++) {
                accQ[fr][fc][e]  += bqv;
                accKi[fr][fc][e] += bkv;
                accKs[fr][fc][e] += bkv;
            }
    }

    // scores: per-row dot(q,k) over this head's 128 cols
    #pragma unroll
    for (int fr = 0; fr < 2; fr++)
        #pragma unroll
        for (int e = 0; e < 4; e++) {
            float d0 = 0.f, d1 = 0.f;
            #pragma unroll
            for (int fc = 0; fc < 4; fc++) {
                d0 += accQ[fr][fc][e] * accKi[fr][fc][e];
                d1 += accQ[fr][fc][e] * accKs[fr][fc][e];
            }
            #pragma unroll
            for (int m = 1; m < 16; m <<= 1) {
                d0 += __shfl_xor(d0, m, 64);
                d1 += __shfl_xor(d1, m, 64);
            }
            if (l16 == 0) {
                int row = wr * 32 + fr * 16 + lq * 4 + e;
                sdot[0][row][wc] = d0;
                sdot[1][row][wc] = d1;
            }
        }
    __syncthreads();
    if (tid < 64) {
        const float scale = 0.088388347648318447f;  // 1/sqrt(128)
        float s0 = (sdot[0][tid][0] + sdot[0][tid][1]) * scale;
        float s1 = (sdot[1][tid][0] + sdot[1][tid][1]) * scale;
        sa0[tid] = 1.0f / (1.0f + expf(s1 - s0));
    }
    __syncthreads();

    // ctx = a0*Vimg + a1*Vsig + bv, written f16
    #pragma unroll
    for (int fc = 0; fc < 4; fc++) {
        int col = col0 + wc * 64 + fc * 16 + l16;
        float bvv = bv[col];
        #pragma unroll
        for (int fr = 0; fr < 2; fr++)
            #pragma unroll
            for (int e = 0; e < 4; e++) {
                int row = wr * 32 + fr * 16 + lq * 4 + e;
                float a0 = sa0[row];
                float v  = a0 * accVi[fr][fc][e] + (1.0f - a0) * accVs[fr][fc][e] + bvv;
                ctx[(size_t)(row0 + row) * E_ + col] = (f16)v;
            }
    }
}

// ---------------- out projection: attn16 = ctx @ Wo^T + bo   (f16) ----------------
// 128x128 tile, BK=32, THREE LDS buffers with counted vmcnt (T4: never drain to 0):
//   issue stage(t+2) -> s_waitcnt vmcnt(4) (waits stage(t+1), keeps t+2 in flight)
//   -> s_barrier -> compute(t).
// 48 KB LDS -> 3 blocks/CU; __launch_bounds__(256,3). col-panel = bid&7 (per-XCD
// Wo L2 residence). r3's dbuf failure used drain-0, which catalog says ~= 1-phase;
// counted wait is the untried lever for the drain-serialized HBM-burst model.
__global__ __launch_bounds__(256, 3) void out_proj_kernel(
    const f16* __restrict__ A, const f16* __restrict__ Wo, const float* __restrict__ bo,
    f16* __restrict__ a16)
{
    __shared__ f16 sA[3][128][32];   // 8 KB per buf -> 24 KB
    __shared__ f16 sB[3][128][32];   //                 24 KB  (48 KB total)
    const int tid  = threadIdx.x;
    const int lane = tid & 63;
    const int wave = tid >> 6;
    const int wr = wave >> 1, wc = wave & 1;
    const int l16 = lane & 15, lq = lane >> 4;

    const int bid  = blockIdx.x;
    const int col0 = (bid & 7) * 128;
    const int row0 = (bid >> 3) * 128;

    const int lr = lane >> 2;
    const int lc = ((lane & 3) ^ ((lane >> 3) & 3)) * 8;   // swizzled source chunk
    const int rc = (lq ^ ((l16 >> 1) & 3)) * 8;            // swizzled read col

    const f16* gA0 = A  + (size_t)(row0 + wave * 32 + lr) * E_ + lc;
    const f16* gB0 = Wo + (size_t)(col0 + wave * 32 + lr) * E_ + lc;
    const size_t wskip = (size_t)16 * E_;

    f32x4 zero4 = {0.f, 0.f, 0.f, 0.f};
    f32x4 acc[4][4];
    #pragma unroll
    for (int i = 0; i < 4; i++)
        #pragma unroll
        for (int j = 0; j < 4; j++) acc[i][j] = zero4;

    auto stage = [&](int b, int kk) {   // 4 gload16 per wave
        gload16(gA0 + kk,         &sA[b][wave * 32][0]);
        gload16(gA0 + wskip + kk, &sA[b][wave * 32 + 16][0]);
        gload16(gB0 + kk,         &sB[b][wave * 32][0]);
        gload16(gB0 + wskip + kk, &sB[b][wave * 32 + 16][0]);
    };

    stage(0, 0);
    stage(1, 32);
    asm volatile("s_waitcnt vmcnt(4)" ::: "memory");   // buf0 resident, buf1 in flight
    __builtin_amdgcn_s_barrier();

    const int NT = E_ / 32;   // 32
    #pragma unroll
    for (int t = 0; t < NT; ++t) {
        const int cur = t % 3;
        if (t + 2 < NT) stage((t + 2) % 3, (t + 2) * 32);   // overwrites buf computed at t-1

        f16x8 aF[4], bF[4];
        #pragma unroll
        for (int f = 0; f < 4; f++) {
            aF[f] = *(const f16x8*)&sA[cur][wr * 64 + f * 16 + l16][rc];
            bF[f] = *(const f16x8*)&sB[cur][wc * 64 + f * 16 + l16][rc];
        }
        #pragma unroll
        for (int fr = 0; fr < 4; fr++)
            #pragma unroll
            for (int fc = 0; fc < 4; fc++)
                acc[fr][fc] = __builtin_amdgcn_mfma_f32_16x16x32_f16(aF[fr], bF[fc], acc[fr][fc], 0, 0, 0);

        if (t + 2 < NT) {
            asm volatile("s_waitcnt vmcnt(4)" ::: "memory");   // buf(t+1) ready; t+2 stays in flight
            __builtin_amdgcn_s_barrier();
        } else if (t + 1 < NT) {
            asm volatile("s_waitcnt vmcnt(0)" ::: "memory");   // last prefetch: drain
            __builtin_amdgcn_s_barrier();
        }
    }

    #pragma unroll
    for (int fc = 0; fc < 4; fc++) {
        int col = col0 + wc * 64 + fc * 16 + l16;
        float bov = bo[col];
        #pragma unroll
        for (int fr = 0; fr < 4; fr++)
            #pragma unroll
            for (int e = 0; e < 4; e++) {
                int row = row0 + wr * 64 + fr * 16 + lq * 4 + e;
                a16[(size_t)row * E_ + col] = (f16)(acc[fr][fc][e] + bov);
            }
    }
}

// ---------------- resid-add + LayerNorm over E=1024 ----------------
// reads attn16 (f16) + image16 (f16 residual); writes normalized f32
__global__ __launch_bounds__(256) void ln_kernel(
    const f16* __restrict__ a16, const f16* __restrict__ resid16,
    const float* __restrict__ gamma, const float* __restrict__ beta,
    float* __restrict__ out)
{
    const int row = blockIdx.x;
    const int tid = threadIdx.x;
    union { ushort4 u; f16 h[4]; } ua, ur;
    ua.u = ((const ushort4*)(a16     + (size_t)row * E_))[tid];
    ur.u = ((const ushort4*)(resid16 + (size_t)row * E_))[tid];
    float4 v;
    v.x = (float)ua.h[0] + (float)ur.h[0];
    v.y = (float)ua.h[1] + (float)ur.h[1];
    v.z = (float)ua.h[2] + (float)ur.h[2];
    v.w = (float)ua.h[3] + (float)ur.h[3];
    float s  = v.x + v.y + v.z + v.w;
    float s2 = v.x * v.x + v.y * v.y + v.z * v.z + v.w * v.w;
    #pragma unroll
    for (int m = 1; m < 64; m <<= 1) {
        s  += __shfl_xor(s, m, 64);
        s2 += __shfl_xor(s2, m, 64);
    }
    __shared__ float red[8];
    int wv = tid >> 6, ln = tid & 63;
    if (ln == 0) { red[wv] = s; red[4 + wv] = s2; }
    __syncthreads();
    s  = red[0] + red[1] + red[2] + red[3];
    s2 = red[4] + red[5] + red[6] + red[7];
    float mu  = s * (1.0f / E_);
    float var = s2 * (1.0f / E_) - mu * mu;
    float r   = rsqrtf(var + 1e-5f);
    float4 g  = ((const float4*)gamma)[tid];
    float4 bb = ((const float4*)beta)[tid];
    float4 o;
    o.x = (v.x - mu) * r * g.x + bb.x;
    o.y = (v.y - mu) * r * g.y + bb.y;
    o.z = (v.z - mu) * r * g.z + bb.z;
    o.w = (v.w - mu) * r * g.w + bb.w;
    ((float4*)(out + (size_t)row * E_))[tid] = o;
}

extern "C" void kernel_launch(void* const* d_in, const int* in_sizes, int n_in,
                              void* d_out, int out_size, void* d_ws, size_t ws_size,
                              hipStream_t stream)
{
    (void)in_sizes; (void)n_in; (void)out_size; (void)ws_size;
    const float* image  = (const float*)d_in[0];
    const float* signal = (const float*)d_in[1];
    const float* Wq = (const float*)d_in[2];
    const float* Wk = (const float*)d_in[3];
    const float* Wv = (const float*)d_in[4];
    const float* bq = (const float*)d_in[5];
    const float* bk = (const float*)d_in[6];
    const float* bv = (const float*)d_in[7];
    const float* Wo = (const float*)d_in[8];
    const float* bo = (const float*)d_in[9];
    const float* gamma = (const float*)d_in[10];
    const float* beta  = (const float*)d_in[11];
    float* out = (float*)d_out;

    char* ws = (char*)d_ws;
    f16* Xi16 = (f16*)(ws);                            // 32 MB (image f16; resid for ln)
    f16* Xs16 = (f16*)(ws + 32ull * 1024 * 1024);      // 32 MB (reused as a16 after qkv)
    f16* Wq16 = (f16*)(ws + 64ull * 1024 * 1024);      // 2 MB
    f16* Wk16 = (f16*)(ws + 66ull * 1024 * 1024);      // 2 MB
    f16* Wv16 = (f16*)(ws + 68ull * 1024 * 1024);      // 2 MB
    f16* Wo16 = (f16*)(ws + 70ull * 1024 * 1024);      // 2 MB
    f16* ctx  = (f16*)(ws + 72ull * 1024 * 1024);      // 32 MB  (total 104 MB)
    f16* a16  = Xs16;                                  // Xs16 dead after qkv

    // one conversion launch: blocks [0,16384) Xi, [16384,32768) Xs, then 4x1024 weights
    cvt6_kernel<<<32768 + 4096, 256, 0, stream>>>(
        (const float4*)image, (const float4*)signal,
        (const float4*)Wq, (const float4*)Wk, (const float4*)Wv, (const float4*)Wo,
        (ushort4*)Xi16, (ushort4*)Xs16,
        (ushort4*)Wq16, (ushort4*)Wk16, (ushort4*)Wv16, (ushort4*)Wo16);

    dim3 g2(B_ / 64, H_);
    qkv_attn_kernel<<<g2, 256, 0, stream>>>(Xi16, Xs16, Wq16, Wk16, Wv16,
                                            bq, bk, bv, ctx);

    out_proj_kernel<<<B_ / 128 * 8, 256, 0, stream>>>(ctx, Wo16, bo, a16);

    ln_kernel<<<B_, 256, 0, stream>>>(a16, Xi16, gamma, beta, out);
}

// Round 8
// 430.446 us; speedup vs baseline: 1.0560x; 1.0560x over previous
//
#include <hip/hip_runtime.h>

#define B_ 16384
#define E_ 1024
#define H_ 8
#define D_ 128

typedef _Float16 f16;
typedef _Float16 f16x8 __attribute__((ext_vector_type(8)));
typedef float f32x4 __attribute__((ext_vector_type(4)));

// async global -> LDS, 16B per lane. LDS dest is wave-uniform base + lane*16.
__device__ __forceinline__ void gload16(const f16* g, f16* l) {
    __builtin_amdgcn_global_load_lds(
        (const __attribute__((address_space(1))) void*)g,
        (__attribute__((address_space(3))) void*)l, 16, 0, 0);
}

// LDS XOR swizzle (within each 16-row x 32-col f16 tile staged by one gload16):
//   LDS chunk p (16B) of row r holds global chunk p ^ ((r>>1)&3).
// Write side: lane l (r=l>>2, p=l&3) sources global chunk (l&3)^((l>>3)&3).
// Read side: global chunk lq of row r lives at LDS chunk lq^((r>>1)&3).
// Verified round 2: SQ_LDS_BANK_CONFLICT 1.68e7 -> 0.
// Template laws measured this session:
//  - 1-phase single-buffer BK=64 beats dbuf-drain0 (r3) AND counted-vmcnt 3buf (r7).
//  - out_proj time is invariant across 6 structural variants -> stop iterating there.
//  - qkv is work/structure-bound at ~873 TF; this round cuts its MFMA work 20%
//    algebraically (score difference + affine mix need only 4 accumulator sets).

// ---------------- f32 -> f16 conversion ----------------
__global__ __launch_bounds__(256) void cvt2_kernel(const float4* __restrict__ s0,
                                                   const float4* __restrict__ s1,
                                                   ushort4* __restrict__ d0,
                                                   ushort4* __restrict__ d1, int n4) {
    const float4* s = blockIdx.y ? s1 : s0;
    ushort4* d = blockIdx.y ? d1 : d0;
    int i = blockIdx.x * 256 + threadIdx.x;
    if (i >= n4) return;
    float4 v = s[i];
    union { ushort4 u; f16 h[4]; } o;
    o.h[0] = (f16)v.x; o.h[1] = (f16)v.y; o.h[2] = (f16)v.z; o.h[3] = (f16)v.w;
    d[i] = o.u;
}

__global__ __launch_bounds__(256) void cvt4_kernel(
    const float4* __restrict__ s0, const float4* __restrict__ s1,
    const float4* __restrict__ s2, const float4* __restrict__ s3,
    ushort4* __restrict__ d0, ushort4* __restrict__ d1,
    ushort4* __restrict__ d2, ushort4* __restrict__ d3, int n4) {
    const float4* s; ushort4* d;
    switch (blockIdx.y) {
        case 0: s = s0; d = d0; break;
        case 1: s = s1; d = d1; break;
        case 2: s = s2; d = d2; break;
        default: s = s3; d = d3; break;
    }
    int i = blockIdx.x * 256 + threadIdx.x;
    if (i >= n4) return;
    float4 v = s[i];
    union { ushort4 u; f16 h[4]; } o;
    o.h[0] = (f16)v.x; o.h[1] = (f16)v.y; o.h[2] = (f16)v.z; o.h[3] = (f16)v.w;
    d[i] = o.u;
}

// ---------------- fused single-pass QKV + 2-key attention -> ctx ----------------
// 1-D grid of 2048 blocks; head = bid & 7, rblk = bid >> 3 (r6-best config).
// 256 threads = 4 waves, wave grid 2x2 over 64 rows x 128 head cols.
// 4 accumulator sets via softmax algebra:
//   D  = Xi - Xs (in-register f16 subtract)
//   accQ  = Xi@Wq  (+bq)          accKd = D@Wk   (bk cancels in s0-s1)
//   accVs = Xs@Wv  (+bv later)    accVd = D@Wv
//   delta = scale * q.kd ;  a0 = sigmoid(delta) ;  ctx = Vs + a0*Vd + bv
// = 64 MFMA per K64 step (was 80), 128 acc VGPRs (was 160).
__global__ __launch_bounds__(256, 2) void qkv_attn_kernel(
    const f16* __restrict__ Xi, const f16* __restrict__ Xs,
    const f16* __restrict__ Wq, const f16* __restrict__ Wk, const f16* __restrict__ Wv,
    const float* __restrict__ bq, const float* __restrict__ bk, const float* __restrict__ bv,
    f16* __restrict__ ctx)
{
    (void)bk;  // cancels in the score difference
    __shared__ f16 sAi[2][64][32];    // [half][row][col]  8 KB
    __shared__ f16 sAs[2][64][32];    //                   8 KB
    __shared__ f16 sWq[2][128][32];   //                  16 KB
    __shared__ f16 sWk[2][128][32];   //                  16 KB
    __shared__ f16 sWv[2][128][32];   //                  16 KB  (64 KB -> 2 blocks/CU)
    __shared__ float sdot[64][2];
    __shared__ float sa0[64];

    const int tid  = threadIdx.x;
    const int lane = tid & 63;
    const int wave = tid >> 6;
    const int wr = wave >> 1, wc = wave & 1;
    const int l16 = lane & 15, lq = lane >> 4;

    const int bid  = blockIdx.x;
    const int head = bid & 7;
    const int row0 = (bid >> 3) * 64;
    const int col0 = head * D_;

    const int lr = lane >> 2;                                   // 0..15
    const int lc = ((lane & 3) ^ ((lane >> 3) & 3)) * 8;        // swizzled src chunk
    const int rc = (lq ^ ((l16 >> 1) & 3)) * 8;                 // swizzled read col

    const f16* gAi = Xi + (size_t)(row0 + wave * 16 + lr) * E_ + lc;
    const f16* gAs = Xs + (size_t)(row0 + wave * 16 + lr) * E_ + lc;
    const size_t woff = (size_t)(col0 + wave * 32 + lr) * E_ + lc;
    const f16* gWq = Wq + woff;
    const f16* gWk = Wk + woff;
    const f16* gWv = Wv + woff;
    const size_t wskip = (size_t)16 * E_;

    f32x4 zero4 = {0.f, 0.f, 0.f, 0.f};
    f32x4 accQ[2][4], accKd[2][4], accVd[2][4], accVs[2][4];
    #pragma unroll
    for (int i = 0; i < 2; i++)
        #pragma unroll
        for (int j = 0; j < 4; j++) {
            accQ[i][j] = zero4; accKd[i][j] = zero4;
            accVd[i][j] = zero4; accVs[i][j] = zero4;
        }

    for (int kk = 0; kk < E_; kk += 64) {
        #pragma unroll
        for (int h = 0; h < 2; h++) {
            const int ko = kk + h * 32;
            gload16(gAi + ko,         &sAi[h][wave * 16][0]);
            gload16(gAs + ko,         &sAs[h][wave * 16][0]);
            gload16(gWq + ko,         &sWq[h][wave * 32][0]);
            gload16(gWq + wskip + ko, &sWq[h][wave * 32 + 16][0]);
            gload16(gWk + ko,         &sWk[h][wave * 32][0]);
            gload16(gWk + wskip + ko, &sWk[h][wave * 32 + 16][0]);
            gload16(gWv + ko,         &sWv[h][wave * 32][0]);
            gload16(gWv + wskip + ko, &sWv[h][wave * 32 + 16][0]);
        }
        __syncthreads();   // drains vmcnt -> tile resident

        #pragma unroll
        for (int h = 0; h < 2; h++) {
            f16x8 aI[2], aS[2], aD[2], bF[4];
            #pragma unroll
            for (int fr = 0; fr < 2; fr++) {
                aI[fr] = *(const f16x8*)&sAi[h][wr * 32 + fr * 16 + l16][rc];
                aS[fr] = *(const f16x8*)&sAs[h][wr * 32 + fr * 16 + l16][rc];
                aD[fr] = aI[fr] - aS[fr];                      // D = Xi - Xs (packed f16)
            }
            // Q = Xi @ Wq
            #pragma unroll
            for (int fc = 0; fc < 4; fc++)
                bF[fc] = *(const f16x8*)&sWq[h][wc * 64 + fc * 16 + l16][rc];
            #pragma unroll
            for (int fr = 0; fr < 2; fr++)
                #pragma unroll
                for (int fc = 0; fc < 4; fc++)
                    accQ[fr][fc] = __builtin_amdgcn_mfma_f32_16x16x32_f16(aI[fr], bF[fc], accQ[fr][fc], 0, 0, 0);
            // Kd = D @ Wk
            #pragma unroll
            for (int fc = 0; fc < 4; fc++)
                bF[fc] = *(const f16x8*)&sWk[h][wc * 64 + fc * 16 + l16][rc];
            #pragma unroll
            for (int fr = 0; fr < 2; fr++)
                #pragma unroll
                for (int fc = 0; fc < 4; fc++)
                    accKd[fr][fc] = __builtin_amdgcn_mfma_f32_16x16x32_f16(aD[fr], bF[fc], accKd[fr][fc], 0, 0, 0);
            // Vs = Xs @ Wv ; Vd = D @ Wv
            #pragma unroll
            for (int fc = 0; fc < 4; fc++)
                bF[fc] = *(const f16x8*)&sWv[h][wc * 64 + fc * 16 + l16][rc];
            #pragma unroll
            for (int fr = 0; fr < 2; fr++)
                #pragma unroll
                for (int fc = 0; fc < 4; fc++) {
                    accVs[fr][fc] = __builtin_amdgcn_mfma_f32_16x16x32_f16(aS[fr], bF[fc], accVs[fr][fc], 0, 0, 0);
                    accVd[fr][fc] = __builtin_amdgcn_mfma_f32_16x16x32_f16(aD[fr], bF[fc], accVd[fr][fc], 0, 0, 0);
                }
        }
        __syncthreads();   // guard LDS reuse next iteration
    }

    // bq on Q (enters delta via q.kd); bk cancels; bv applied in epilogue
    #pragma unroll
    for (int fc = 0; fc < 4; fc++) {
        int col = col0 + wc * 64 + fc * 16 + l16;
        float bqv = bq[col];
        #pragma unroll
        for (int fr = 0; fr < 2; fr++)
            #pragma unroll
            for (int e = 0; e < 4; e++)
                accQ[fr][fc][e] += bqv;
    }

    // delta per row = scale * sum_cols q*kd   (C layout: col=l16, row=lq*4+e)
    #pragma unroll
    for (int fr = 0; fr < 2; fr++)
        #pragma unroll
        for (int e = 0; e < 4; e++) {
            float d = 0.f;
            #pragma unroll
            for (int fc = 0; fc < 4; fc++)
                d += accQ[fr][fc][e] * accKd[fr][fc][e];
            #pragma unroll
            for (int m = 1; m < 16; m <<= 1)
                d += __shfl_xor(d, m, 64);
            if (l16 == 0) {
                int row = wr * 32 + fr * 16 + lq * 4 + e;
                sdot[row][wc] = d;
            }
        }
    __syncthreads();
    if (tid < 64) {
        const float scale = 0.088388347648318447f;  // 1/sqrt(128)
        float delta = (sdot[tid][0] + sdot[tid][1]) * scale;   // s0 - s1
        sa0[tid] = 1.0f / (1.0f + expf(-delta));
    }
    __syncthreads();

    // ctx = Vs + a0*Vd + bv, written f16
    #pragma unroll
    for (int fc = 0; fc < 4; fc++) {
        int col = col0 + wc * 64 + fc * 16 + l16;
        float bvv = bv[col];
        #pragma unroll
        for (int fr = 0; fr < 2; fr++)
            #pragma unroll
            for (int e = 0; e < 4; e++) {
                int row = wr * 32 + fr * 16 + lq * 4 + e;
                float a0 = sa0[row];
                float v  = fmaf(a0, accVd[fr][fc][e], accVs[fr][fc][e]) + bvv;
                ctx[(size_t)(row0 + row) * E_ + col] = (f16)v;
            }
    }
}

// ---------------- out projection: attn16 = ctx @ Wo^T + bo   (f16) ----------------
// r6-best variant: 128x128 tile, BK=64 single-buffer 1-phase, 4 blocks/CU,
// col-panel = bid&7 (per-XCD Wo L2 residence).
__global__ __launch_bounds__(256, 4) void out_proj_kernel(
    const f16* __restrict__ A, const f16* __restrict__ Wo, const float* __restrict__ bo,
    f16* __restrict__ a16)
{
    __shared__ f16 sA[2][128][32];   // [half][row][col] 16 KB
    __shared__ f16 sB[2][128][32];   //                  16 KB
    const int tid  = threadIdx.x;
    const int lane = tid & 63;
    const int wave = tid >> 6;
    const int wr = wave >> 1, wc = wave & 1;
    const int l16 = lane & 15, lq = lane >> 4;

    const int bid  = blockIdx.x;
    const int col0 = (bid & 7) * 128;
    const int row0 = (bid >> 3) * 128;

    const int lr = lane >> 2;
    const int lc = ((lane & 3) ^ ((lane >> 3) & 3)) * 8;   // swizzled source chunk
    const int rc = (lq ^ ((l16 >> 1) & 3)) * 8;            // swizzled read col

    const f16* gA0 = A  + (size_t)(row0 + wave * 32 + lr) * E_ + lc;
    const f16* gB0 = Wo + (size_t)(col0 + wave * 32 + lr) * E_ + lc;
    const size_t wskip = (size_t)16 * E_;

    f32x4 zero4 = {0.f, 0.f, 0.f, 0.f};
    f32x4 acc[4][4];
    #pragma unroll
    for (int i = 0; i < 4; i++)
        #pragma unroll
        for (int j = 0; j < 4; j++) acc[i][j] = zero4;

    for (int kk = 0; kk < E_; kk += 64) {
        #pragma unroll
        for (int h = 0; h < 2; h++) {
            const int ko = kk + h * 32;
            gload16(gA0 + ko,         &sA[h][wave * 32][0]);
            gload16(gA0 + wskip + ko, &sA[h][wave * 32 + 16][0]);
            gload16(gB0 + ko,         &sB[h][wave * 32][0]);
            gload16(gB0 + wskip + ko, &sB[h][wave * 32 + 16][0]);
        }
        __syncthreads();

        #pragma unroll
        for (int h = 0; h < 2; h++) {
            f16x8 aF[4], bF[4];
            #pragma unroll
            for (int f = 0; f < 4; f++) {
                aF[f] = *(const f16x8*)&sA[h][wr * 64 + f * 16 + l16][rc];
                bF[f] = *(const f16x8*)&sB[h][wc * 64 + f * 16 + l16][rc];
            }
            #pragma unroll
            for (int fr = 0; fr < 4; fr++)
                #pragma unroll
                for (int fc = 0; fc < 4; fc++)
                    acc[fr][fc] = __builtin_amdgcn_mfma_f32_16x16x32_f16(aF[fr], bF[fc], acc[fr][fc], 0, 0, 0);
        }
        __syncthreads();
    }

    #pragma unroll
    for (int fc = 0; fc < 4; fc++) {
        int col = col0 + wc * 64 + fc * 16 + l16;
        float bov = bo[col];
        #pragma unroll
        for (int fr = 0; fr < 4; fr++)
            #pragma unroll
            for (int e = 0; e < 4; e++) {
                int row = row0 + wr * 64 + fr * 16 + lq * 4 + e;
                a16[(size_t)row * E_ + col] = (f16)(acc[fr][fc][e] + bov);
            }
    }
}

// ---------------- resid-add + LayerNorm over E=1024 ----------------
// reads attn16 (f16) + image16 (f16 residual); writes normalized f32
__global__ __launch_bounds__(256) void ln_kernel(
    const f16* __restrict__ a16, const f16* __restrict__ resid16,
    const float* __restrict__ gamma, const float* __restrict__ beta,
    float* __restrict__ out)
{
    const int row = blockIdx.x;
    const int tid = threadIdx.x;
    union { ushort4 u; f16 h[4]; } ua, ur;
    ua.u = ((const ushort4*)(a16     + (size_t)row * E_))[tid];
    ur.u = ((const ushort4*)(resid16 + (size_t)row * E_))[tid];
    float4 v;
    v.x = (float)ua.h[0] + (float)ur.h[0];
    v.y = (float)ua.h[1] + (float)ur.h[1];
    v.z = (float)ua.h[2] + (float)ur.h[2];
    v.w = (float)ua.h[3] + (float)ur.h[3];
    float s  = v.x + v.y + v.z + v.w;
    float s2 = v.x * v.x + v.y * v.y + v.z * v.z + v.w * v.w;
    #pragma unroll
    for (int m = 1; m < 64; m <<= 1) {
        s  += __shfl_xor(s, m, 64);
        s2 += __shfl_xor(s2, m, 64);
    }
    __shared__ float red[8];
    int wv = tid >> 6, ln = tid & 63;
    if (ln == 0) { red[wv] = s; red[4 + wv] = s2; }
    __syncthreads();
    s  = red[0] + red[1] + red[2] + red[3];
    s2 = red[4] + red[5] + red[6] + red[7];
    float mu  = s * (1.0f / E_);
    float var = s2 * (1.0f / E_) - mu * mu;
    float r   = rsqrtf(var + 1e-5f);
    float4 g  = ((const float4*)gamma)[tid];
    float4 bb = ((const float4*)beta)[tid];
    float4 o;
    o.x = (v.x - mu) * r * g.x + bb.x;
    o.y = (v.y - mu) * r * g.y + bb.y;
    o.z = (v.z - mu) * r * g.z + bb.z;
    o.w = (v.w - mu) * r * g.w + bb.w;
    ((float4*)(out + (size_t)row * E_))[tid] = o;
}

extern "C" void kernel_launch(void* const* d_in, const int* in_sizes, int n_in,
                              void* d_out, int out_size, void* d_ws, size_t ws_size,
                              hipStream_t stream)
{
    (void)in_sizes; (void)n_in; (void)out_size; (void)ws_size;
    const float* image  = (const float*)d_in[0];
    const float* signal = (const float*)d_in[1];
    const float* Wq = (const float*)d_in[2];
    const float* Wk = (const float*)d_in[3];
    const float* Wv = (const float*)d_in[4];
    const float* bq = (const float*)d_in[5];
    const float* bk = (const float*)d_in[6];
    const float* bv = (const float*)d_in[7];
    const float* Wo = (const float*)d_in[8];
    const float* bo = (const float*)d_in[9];
    const float* gamma = (const float*)d_in[10];
    const float* beta  = (const float*)d_in[11];
    float* out = (float*)d_out;

    char* ws = (char*)d_ws;
    f16* Xi16 = (f16*)(ws);                            // 32 MB (image f16; resid for ln)
    f16* Xs16 = (f16*)(ws + 32ull * 1024 * 1024);      // 32 MB (reused as a16 after qkv)
    f16* Wq16 = (f16*)(ws + 64ull * 1024 * 1024);      // 2 MB
    f16* Wk16 = (f16*)(ws + 66ull * 1024 * 1024);      // 2 MB
    f16* Wv16 = (f16*)(ws + 68ull * 1024 * 1024);      // 2 MB
    f16* Wo16 = (f16*)(ws + 70ull * 1024 * 1024);      // 2 MB
    f16* ctx  = (f16*)(ws + 72ull * 1024 * 1024);      // 32 MB  (total 104 MB)
    f16* a16  = Xs16;                                  // Xs16 dead after qkv

    const int nBE4 = B_ * E_ / 4;   // 4194304
    const int nEE4 = E_ * E_ / 4;   // 262144
    dim3 gX(nBE4 / 256, 2);
    cvt2_kernel<<<gX, 256, 0, stream>>>((const float4*)image, (const float4*)signal,
                                        (ushort4*)Xi16, (ushort4*)Xs16, nBE4);
    dim3 gW(nEE4 / 256, 4);
    cvt4_kernel<<<gW, 256, 0, stream>>>((const float4*)Wq, (const float4*)Wk,
                                        (const float4*)Wv, (const float4*)Wo,
                                        (ushort4*)Wq16, (ushort4*)Wk16,
                                        (ushort4*)Wv16, (ushort4*)Wo16, nEE4);

    qkv_attn_kernel<<<B_ / 64 * H_, 256, 0, stream>>>(Xi16, Xs16, Wq16, Wk16, Wv16,
                                                      bq, bk, bv, ctx);

    out_proj_kernel<<<B_ / 128 * 8, 256, 0, stream>>>(ctx, Wo16, bo, a16);

    ln_kernel<<<B_, 256, 0, stream>>>(a16, Xi16, gamma, beta, out);
}